// Round 1
// baseline (1218.566 us; speedup 1.0000x reference)
//
#include <hip/hip_runtime.h>
#include <hip/hip_bf16.h>

#define NN 50000
#define NE 500000
#define F 128
#define K_IN 128
#define ED 64
#define C 2
#define NEG 0.2f

__device__ __forceinline__ unsigned fkey(float f) {
    unsigned b = __float_as_uint(f);
    return (b & 0x80000000u) ? ~b : (b | 0x80000000u);
}
__device__ __forceinline__ float funkey(unsigned u) {
    unsigned b = (u & 0x80000000u) ? (u & 0x7fffffffu) : ~u;
    return __uint_as_float(b);
}

__global__ void init_kernel(unsigned* __restrict__ mkey, float* __restrict__ s, int n) {
    int i = blockIdx.x * blockDim.x + threadIdx.x;
    if (i < n) { mkey[i] = fkey(-__builtin_inff()); s[i] = 0.f; }
}

// x_base[n][f] = sum_k x[n][k] * W_l[f][k]
__global__ __launch_bounds__(256) void proj_kernel(const float* __restrict__ x,
                                                   const float* __restrict__ W_l,
                                                   float* __restrict__ xb,
                                                   int nodes_per_block) {
    __shared__ float Wt[K_IN][F]; // Wt[k][f] = W_l[f][k], 64KB
    for (int i = threadIdx.x; i < F * K_IN; i += 256) {
        int f = i & (F - 1), k = i >> 7;
        Wt[k][f] = W_l[f * K_IN + k]; // strided read (L1/L2 cached), conflict-free write
    }
    __syncthreads();
    int node0 = blockIdx.x * nodes_per_block;
    int node_end = min(node0 + nodes_per_block, NN);
    int half = threadIdx.x >> 7; // 0..1
    int f = threadIdx.x & (F - 1);
    for (int n = node0 + half; n < node_end; n += 2) {
        const float* xr = x + (size_t)n * K_IN;
        float acc = 0.f;
#pragma unroll 8
        for (int k = 0; k < K_IN; ++k)
            acc = fmaf(xr[k], Wt[k][f], acc);
        xb[(size_t)n * F + f] = acc;
    }
}

// per-edge logits + segment max (atomicMax on ordered-int key)
__global__ __launch_bounds__(256) void edge_logits_kernel(
    const int* __restrict__ ei, const float* __restrict__ ea,
    const float* __restrict__ xb, const float* __restrict__ W_e,
    const float* __restrict__ cb, const float* __restrict__ att,
    const float* __restrict__ att_sc, const float* __restrict__ ebias,
    float* __restrict__ logits, unsigned* __restrict__ mkey) {
    __shared__ float WeT[ED][F]; // WeT[k][f] = W_e[f][k], 32KB
    __shared__ float att_s[F];
    __shared__ float cb_s[C][F];
    __shared__ float eb_s[C][F];
    for (int i = threadIdx.x; i < ED * F; i += 256) {
        int f = i & (F - 1), k = i >> 7;
        WeT[k][f] = W_e[f * ED + k];
    }
    for (int i = threadIdx.x; i < F; i += 256) att_s[i] = att[i];
    for (int i = threadIdx.x; i < C * F; i += 256) {
        int c = i >> 7, f = i & (F - 1);
        cb_s[c][f] = cb[c * F + f];
        eb_s[c][f] = ebias[f * C + c];
    }
    float as0 = att_sc[0], as1 = att_sc[1];
    __syncthreads();

    int lane = threadIdx.x & 63;
    int wid = blockIdx.x * 4 + (threadIdx.x >> 6);
    int stride = gridDim.x * 4;
    for (int e = wid; e < NE; e += stride) {
        int src = ei[e];
        int tgt = ei[NE + e];
        float eav = ea[(size_t)e * ED + lane];
        float emb0 = 0.f, emb1 = 0.f;
#pragma unroll
        for (int k = 0; k < ED; ++k) {
            float a = __shfl(eav, k, 64);
            emb0 = fmaf(a, WeT[k][lane], emb0);
            emb1 = fmaf(a, WeT[k][lane + 64], emb1);
        }
        float xj0 = xb[(size_t)src * F + lane];
        float xj1 = xb[(size_t)src * F + lane + 64];
        float xi0 = xb[(size_t)tgt * F + lane];
        float xi1 = xb[(size_t)tgt * F + lane + 64];
        float p0, p1;
        {
            float t0 = xi0 + cb_s[0][lane] + xj0 + emb0 + eb_s[0][lane];
            float t1 = xi1 + cb_s[0][lane + 64] + xj1 + emb1 + eb_s[0][lane + 64];
            t0 = t0 > 0.f ? t0 : NEG * t0;
            t1 = t1 > 0.f ? t1 : NEG * t1;
            p0 = fmaf(t0, att_s[lane], t1 * att_s[lane + 64]);
        }
        {
            float t0 = xi0 + cb_s[1][lane] + xj0 + emb0 + eb_s[1][lane];
            float t1 = xi1 + cb_s[1][lane + 64] + xj1 + emb1 + eb_s[1][lane + 64];
            t0 = t0 > 0.f ? t0 : NEG * t0;
            t1 = t1 > 0.f ? t1 : NEG * t1;
            p1 = fmaf(t0, att_s[lane], t1 * att_s[lane + 64]);
        }
#pragma unroll
        for (int off = 32; off > 0; off >>= 1) {
            p0 += __shfl_xor(p0, off, 64);
            p1 += __shfl_xor(p1, off, 64);
        }
        if (lane == 0) {
            float l0 = p0 * as0;
            float l1 = p1 * as1;
            logits[2 * (size_t)e] = l0;
            logits[2 * (size_t)e + 1] = l1;
            atomicMax(&mkey[2 * tgt], fkey(l0));
            atomicMax(&mkey[2 * tgt + 1], fkey(l1));
        }
    }
}

// e = exp(l - m[tgt]); s[tgt] += e  (in-place overwrite of logits with e)
__global__ void exp_sum_kernel(const int* __restrict__ ei,
                               float* __restrict__ logits,
                               const unsigned* __restrict__ mkey,
                               float* __restrict__ s) {
    int i = blockIdx.x * blockDim.x + threadIdx.x;
    if (i >= NE * C) return;
    int e = i >> 1, c = i & 1;
    int tgt = ei[NE + e];
    float m = funkey(mkey[2 * tgt + c]);
    float ev = expf(logits[i] - m);
    logits[i] = ev;
    atomicAdd(&s[2 * tgt + c], ev);
}

// alpha = e/(s+eps); msgs scatter-add; alpha output
__global__ __launch_bounds__(256) void agg_kernel(
    const int* __restrict__ ei, const float* __restrict__ ea,
    const float* __restrict__ xb, const float* __restrict__ W_e,
    const float* __restrict__ ebias, const float* __restrict__ evals,
    const float* __restrict__ sbuf, float* __restrict__ out,
    float* __restrict__ alpha_out) {
    __shared__ float WeT[ED][F];
    __shared__ float eb_s[C][F];
    for (int i = threadIdx.x; i < ED * F; i += 256) {
        int f = i & (F - 1), k = i >> 7;
        WeT[k][f] = W_e[f * ED + k];
    }
    for (int i = threadIdx.x; i < C * F; i += 256) {
        int c = i >> 7, f = i & (F - 1);
        eb_s[c][f] = ebias[f * C + c];
    }
    __syncthreads();

    int lane = threadIdx.x & 63;
    int wid = blockIdx.x * 4 + (threadIdx.x >> 6);
    int stride = gridDim.x * 4;
    for (int e = wid; e < NE; e += stride) {
        int src = ei[e];
        int tgt = ei[NE + e];
        float a0 = evals[2 * (size_t)e] / (sbuf[2 * tgt] + 1e-16f);
        float a1 = evals[2 * (size_t)e + 1] / (sbuf[2 * tgt + 1] + 1e-16f);
        if (lane == 0) {
            alpha_out[2 * (size_t)e] = a0;
            alpha_out[2 * (size_t)e + 1] = a1;
        }
        float eav = ea[(size_t)e * ED + lane];
        float emb0 = 0.f, emb1 = 0.f;
#pragma unroll
        for (int k = 0; k < ED; ++k) {
            float a = __shfl(eav, k, 64);
            emb0 = fmaf(a, WeT[k][lane], emb0);
            emb1 = fmaf(a, WeT[k][lane + 64], emb1);
        }
        float xj0 = xb[(size_t)src * F + lane];
        float xj1 = xb[(size_t)src * F + lane + 64];
        float base0 = xj0 + emb0;
        float base1 = xj1 + emb1;
        float* orow = out + (size_t)tgt * (C * F);
        atomicAdd(orow + lane, (base0 + eb_s[0][lane]) * a0);
        atomicAdd(orow + F + lane, (base0 + eb_s[1][lane]) * a1);
        atomicAdd(orow + 64 + lane, (base1 + eb_s[0][lane + 64]) * a0);
        atomicAdd(orow + 192 + lane, (base1 + eb_s[1][lane + 64]) * a1);
    }
}

extern "C" void kernel_launch(void* const* d_in, const int* in_sizes, int n_in,
                              void* d_out, int out_size, void* d_ws, size_t ws_size,
                              hipStream_t stream) {
    const float* x      = (const float*)d_in[0];
    const int*   ei     = (const int*)d_in[1];
    const float* ea     = (const float*)d_in[2];
    const float* W_l    = (const float*)d_in[3];
    const float* cb     = (const float*)d_in[4];
    const float* att    = (const float*)d_in[5];
    const float* att_sc = (const float*)d_in[6];
    const float* W_e    = (const float*)d_in[7];
    const float* ebias  = (const float*)d_in[8];

    float* out = (float*)d_out;
    float* alpha_out = out + (size_t)NN * C * F; // 12.8M offset

    float* ws = (float*)d_ws;
    float* xb      = ws;                 // 6.4M floats
    float* logits  = ws + 6400000;       // 1.0M floats (becomes e-values)
    unsigned* mkey = (unsigned*)(ws + 7400000); // 100K
    float* sbuf    = ws + 7500000;       // 100K

    // zero agg region of out (alpha region fully overwritten)
    hipMemsetAsync(out, 0, (size_t)NN * C * F * sizeof(float), stream);
    init_kernel<<<(NN * C + 255) / 256, 256, 0, stream>>>(mkey, sbuf, NN * C);

    proj_kernel<<<1000, 256, 0, stream>>>(x, W_l, xb, 50);

    edge_logits_kernel<<<1024, 256, 0, stream>>>(ei, ea, xb, W_e, cb, att,
                                                 att_sc, ebias, logits, mkey);

    exp_sum_kernel<<<(NE * C + 255) / 256, 256, 0, stream>>>(ei, logits, mkey, sbuf);

    agg_kernel<<<1024, 256, 0, stream>>>(ei, ea, xb, W_e, ebias, logits, sbuf,
                                         out, alpha_out);
}